// Round 7
// baseline (138.781 us; speedup 1.0000x reference)
//
#include <hip/hip_runtime.h>
#include <math.h>

#define U_ 4096
#define T_ 200
#define K_ 64
#define Q_ 10000
#define H_ 128
#define UPB 8    // users (waves) per block in scan
#define PPB 32   // pairs per block in mlp (625 blocks x 32 = 20000)

__device__ __forceinline__ float gelu_f(float x) {
  // exact erf GELU (matches jax.nn.gelu approximate=False)
  return 0.5f * x * (1.0f + erff(x * 0.70710678118654752440f));
}

// ---------------------------------------------------------------------------
// K1 (R7): MLP table over (q, resp) -> tab4[2q+rp] = (r, mu, ts, td)
// + fused kc_of_q. 625 blocks x 32 pairs: each staged W2 half (32 KB) now
// serves 32 pairs (R4: 16), wave owns 8 pairs -> 16 fma per 10 LDS reads.
// h1buf padded to 129 (2-way bank alias only). 48.6 KB LDS -> 3 blocks/CU.
// ---------------------------------------------------------------------------
__global__ __launch_bounds__(256, 4) void mlp_table_kernel(
    const float* __restrict__ diff_mu, const float* __restrict__ disc_mu,
    const float* __restrict__ W1, const float* __restrict__ b1,
    const float* __restrict__ W2, const float* __restrict__ b2,
    const float* __restrict__ W3, const float* __restrict__ b3,
    const unsigned char* __restrict__ kmap,
    float4* __restrict__ tab4, int* __restrict__ kc_of_q) {
  __shared__ float W2s[64 * H_];          // 32 KB: one half of W2
  __shared__ float h1buf[PPB][H_ + 1];    // 16.5 KB, pad->129

  const int tid = threadIdx.x;
  const int lane = tid & 63, w = tid >> 6;
  const int base = blockIdx.x * PPB;

  // fused kc_of_q: first 40 blocks cover Q=10000
  if (blockIdx.x < 40) {
    int q = blockIdx.x * 256 + tid;
    if (q < Q_) {
      const unsigned char* km = kmap + (size_t)q * K_;
      int kc = 0;
#pragma unroll
      for (int k = 0; k < K_; ++k)
        if (km[k]) kc = k;  // one-hot
      kc_of_q[q] = kc;
    }
  }

  // layer 1: 32 pairs x 128 hidden
  for (int v = tid; v < PPB * H_; v += 256) {
    int pl = v >> 7, j = v & 127;
    int pg = base + pl, q = pg >> 1;
    float rf = (float)(pg & 1);
    float a = fmaf(diff_mu[q], W1[j], b1[j]);
    a = fmaf(disc_mu[q], W1[H_ + j], a);
    a = fmaf(rf, W1[2 * H_ + j], a);
    h1buf[pl][j] = gelu_f(a);
  }
  // stage W2 rows 0..63 (float4 coalesced)
  for (int v = tid; v < 2048; v += 256)
    ((float4*)W2s)[v] = ((const float4*)W2)[v];
  __syncthreads();

  float a0[8], a1[8];
#pragma unroll
  for (int p = 0; p < 8; ++p) { a0[p] = 0.f; a1[p] = 0.f; }

#pragma clang loop unroll_count(4)
  for (int k = 0; k < 64; ++k) {
    float w0 = W2s[k * H_ + lane];        // 2-way alias: free
    float w1 = W2s[k * H_ + lane + 64];
#pragma unroll
    for (int p = 0; p < 8; ++p) {
      float hv = h1buf[w * 8 + p][k];     // uniform -> broadcast
      a0[p] = fmaf(w0, hv, a0[p]);
      a1[p] = fmaf(w1, hv, a1[p]);
    }
  }
  __syncthreads();
  // stage W2 rows 64..127
  for (int v = tid; v < 2048; v += 256)
    ((float4*)W2s)[v] = ((const float4*)W2)[2048 + v];
  __syncthreads();
#pragma clang loop unroll_count(4)
  for (int k = 0; k < 64; ++k) {
    float w0 = W2s[k * H_ + lane];
    float w1 = W2s[k * H_ + lane + 64];
#pragma unroll
    for (int p = 0; p < 8; ++p) {
      float hv = h1buf[w * 8 + p][64 + k];
      a0[p] = fmaf(w0, hv, a0[p]);
      a1[p] = fmaf(w1, hv, a1[p]);
    }
  }

  // layer 3 + head math: wave w owns pairs w*8 .. w*8+7
  float w30a = W3[lane * 2 + 0], w31a = W3[lane * 2 + 1];
  float w30b = W3[(lane + 64) * 2 + 0], w31b = W3[(lane + 64) * 2 + 1];
  float b2a = b2[lane], b2b = b2[lane + 64];
  float b30 = b3[0], b31 = b3[1];
#pragma unroll
  for (int p = 0; p < 8; ++p) {
    float h2a = gelu_f(a0[p] + b2a);
    float h2b = gelu_f(a1[p] + b2b);
    float s0 = h2a * w30a + h2b * w30b;
    float s1 = h2a * w31a + h2b * w31b;
#pragma unroll
    for (int off = 32; off > 0; off >>= 1) {
      s0 += __shfl_xor(s0, off, 64);
      s1 += __shfl_xor(s1, off, 64);
    }
    if (lane == 0) {
      float mu = gelu_f(s0 + b30);
      float lv = gelu_f(s1 + b31);
      float sd = fmaxf(expf(0.5f * lv), 1e-8f);
      int pg = base + w * 8 + p;
      int q = pg >> 1;
      tab4[pg] = make_float4(1.0f / (sd * sd), mu, disc_mu[q], diff_mu[q]);
    }
  }
}

// ---------------------------------------------------------------------------
// K2 (R7): barrier-free scan. Wave = user; LDS column bcs[.][ul] is touched
// ONLY by wave ul -> no __syncthreads anywhere (intra-wave DS ops are
// in-order, same guarantee R5/R6's passing forward chains relied on).
// Backward runs lane-replicated on EVERY wave (uniform LDS broadcasts, no
// readlane SGPR hazards, no idle waves); (b,c) captured to register tiles
// via cndmask, then 4 bulk ds_writes. Forward = lane=KC per wave (R6).
// ---------------------------------------------------------------------------
__global__ __launch_bounds__(512) void scan_kernel(
    const int* __restrict__ q_id, const int* __restrict__ resp,
    const float4* __restrict__ tab4, const int* __restrict__ kc_of_q,
    float* __restrict__ out) {
  __shared__ float2 bcs[T_ * (UPB + 1)];   // [t][u], u-stride 9 (wave-private col)
  __shared__ unsigned char kcs[T_ * UPB];  // [t][u]

  const int tid = threadIdx.x;
  const int lane = tid & 63;
  const int ul = tid >> 6;
  const int gu = blockIdx.x * UPB + ul;

  // ---- P0: gather (coalesced q/resp; tab4+kc L2/L3-resident) ----
  float tts[4], ttd[4];
  const int* qrow = q_id + (size_t)gu * T_;
  const int* rrow = resp + (size_t)gu * T_;
#pragma unroll
  for (int i = 0; i < 4; ++i) {
    int t = i * 64 + lane;
    int tc = t < T_ ? t : T_ - 1;
    int q = qrow[tc];
    int rp = rrow[tc];
    float4 f = tab4[q * 2 + rp];
    tts[i] = f.z;
    ttd[i] = f.w;
    if (t < T_) {
      bcs[t * (UPB + 1) + ul] = make_float2(f.x, f.y);  // (r, mu)
      kcs[t * UPB + ul] = (unsigned char)kc_of_q[q];
    }
  }

  // ---- P1: backward, lane-replicated on every wave ----
  // b = 1/(2 + r - b_next); c = b*(c_next + r*mu)  (passing math since R3)
  float tb[4], tcc[4];
  float b = 1.0f, c = 0.0f;
#pragma unroll 8
  for (int s = 7; s >= 0; --s) {           // tile 3: t = 199..192
    int t = 192 + s;
    float2 rm = bcs[t * (UPB + 1) + ul];   // uniform -> LDS broadcast
    float x_ = 2.0f + rm.x - b;
    float ib = __builtin_amdgcn_rcpf(x_);
    ib = ib * (2.0f - x_ * ib);            // Newton step
    b = ib;
    c = b * fmaf(rm.x, rm.y, c);
    bool cap = (lane == s);
    tb[3] = cap ? b : tb[3];
    tcc[3] = cap ? c : tcc[3];
  }
#pragma unroll
  for (int i = 2; i >= 0; --i) {           // static tile index
#pragma unroll 8
    for (int s = 63; s >= 0; --s) {
      int t = i * 64 + s;
      float2 rm = bcs[t * (UPB + 1) + ul];
      float x_ = 2.0f + rm.x - b;
      float ib = __builtin_amdgcn_rcpf(x_);
      ib = ib * (2.0f - x_ * ib);
      b = ib;
      c = b * fmaf(rm.x, rm.y, c);
      bool cap = (lane == s);
      tb[i] = cap ? b : tb[i];
      tcc[i] = cap ? c : tcc[i];
    }
  }
  // bulk writeback (in-order after all chain reads)
#pragma unroll
  for (int i = 0; i < 4; ++i) {
    int t = i * 64 + lane;
    if (t < T_) bcs[t * (UPB + 1) + ul] = make_float2(tb[i], tcc[i]);
  }

  // ---- P2: forward, lane = KC ----
  float x = 0.0f;
#pragma unroll 8
  for (int t = 0; t < T_; ++t) {
    float2 bc_ = bcs[t * (UPB + 1) + ul];  // uniform
    int kc = (int)kcs[t * UPB + ul];       // uniform
    float xn = fmaf(bc_.x, x, bc_.y);
    bool hit = (lane == kc);
    x = hit ? xn : x;
    if (hit) bcs[t * (UPB + 1) + ul].x = xn;  // ability stash (read precedes write)
  }

  // ---- P3: epilogue ----
  float* logits = out;
  float* last = out + (size_t)U_ * T_;
#pragma unroll
  for (int i = 0; i < 4; ++i) {
    int t = i * 64 + lane;
    if (t < T_) {
      float ab = bcs[t * (UPB + 1) + ul].x;
      logits[(size_t)gu * T_ + t] = tts[i] * (ab - ttd[i]);  // coalesced
    }
  }
  last[(size_t)gu * K_ + lane] = x;  // last_ability_kc straight from registers
}

// ---------------------------------------------------------------------------
extern "C" void kernel_launch(void* const* d_in, const int* in_sizes, int n_in,
                              void* d_out, int out_size, void* d_ws,
                              size_t ws_size, hipStream_t stream) {
  // setup_inputs order:
  // 0 mask 1 q_id(i32,U*T) 2 kmap(bool,Q*K) 3 resp(i32) 4 diff_mu 5 disc_mu
  // 6 W1 7 b1 8 W2 9 b2 10 W3 11 b3
  const int* q_id = (const int*)d_in[1];
  const unsigned char* kmap = (const unsigned char*)d_in[2];
  const int* resp = (const int*)d_in[3];
  const float* diff_mu = (const float*)d_in[4];
  const float* disc_mu = (const float*)d_in[5];
  const float* W1 = (const float*)d_in[6];
  const float* b1 = (const float*)d_in[7];
  const float* W2 = (const float*)d_in[8];
  const float* b2 = (const float*)d_in[9];
  const float* W3 = (const float*)d_in[10];
  const float* b3 = (const float*)d_in[11];
  float* out = (float*)d_out;
  char* ws = (char*)d_ws;

  auto align512 = [](size_t x) { return (x + 511) & ~(size_t)511; };
  size_t o = 0;
  float4* tab4 = (float4*)(ws + o);  o = align512(o + (size_t)2 * Q_ * 16);
  int* kc_of_q = (int*)(ws + o);     o = align512(o + (size_t)Q_ * 4);
  (void)ws_size; (void)in_sizes; (void)n_in; (void)out_size;

  mlp_table_kernel<<<Q_ * 2 / PPB, 256, 0, stream>>>(
      diff_mu, disc_mu, W1, b1, W2, b2, W3, b3, kmap, tab4, kc_of_q);
  scan_kernel<<<U_ / UPB, 512, 0, stream>>>(q_id, resp, tab4, kc_of_q, out);
}